// Round 1
// baseline (170.600 us; speedup 1.0000x reference)
//
#include <hip/hip_runtime.h>
#include <hip/hip_bf16.h>

#define NROWS 4096
#define IN_F 512
#define OUT_F 128
#define NBINS 128
#define NCLS 16
#define SIGMA 0.2f
#define EPSV 1e-8f
#define TAUV 0.1f

// ---------------- K1: MLP projection, 4 rows per block ----------------
__global__ __launch_bounds__(128) void proj_kernel(
    const float* __restrict__ X1, const float* __restrict__ X2,
    const float* __restrict__ W1, const float* __restrict__ b1,
    const float* __restrict__ W2, const float* __restrict__ b2,
    float* __restrict__ P)
{
    __shared__ float xs[4][IN_F];
    __shared__ float hs[4][OUT_F];
    const int f = threadIdx.x;
    const int row0 = blockIdx.x * 4;              // global row in [0, 8192)
    const float* X = (row0 < NROWS) ? X1 : X2;
    const int xr0 = (row0 < NROWS) ? row0 : row0 - NROWS;

    // stage 4 rows of X (2048 floats) into LDS, coalesced
    #pragma unroll
    for (int i = 0; i < 16; ++i) {
        int idx = i * 128 + f;
        int r = idx >> 9, k = idx & 511;
        xs[r][k] = X[(size_t)(xr0 + r) * IN_F + k];
    }
    __syncthreads();

    float a0 = 0.f, a1 = 0.f, a2 = 0.f, a3 = 0.f;
    for (int k = 0; k < IN_F; ++k) {
        float w = W1[k * OUT_F + f];
        a0 = fmaf(xs[0][k], w, a0);
        a1 = fmaf(xs[1][k], w, a1);
        a2 = fmaf(xs[2][k], w, a2);
        a3 = fmaf(xs[3][k], w, a3);
    }
    float bb = b1[f];
    hs[0][f] = fmaxf(a0 + bb, 0.f);
    hs[1][f] = fmaxf(a1 + bb, 0.f);
    hs[2][f] = fmaxf(a2 + bb, 0.f);
    hs[3][f] = fmaxf(a3 + bb, 0.f);
    __syncthreads();

    a0 = a1 = a2 = a3 = 0.f;
    for (int k = 0; k < OUT_F; ++k) {
        float w = W2[k * OUT_F + f];
        a0 = fmaf(hs[0][k], w, a0);
        a1 = fmaf(hs[1][k], w, a1);
        a2 = fmaf(hs[2][k], w, a2);
        a3 = fmaf(hs[3][k], w, a3);
    }
    bb = b2[f];
    P[(size_t)(row0 + 0) * OUT_F + f] = a0 + bb;
    P[(size_t)(row0 + 1) * OUT_F + f] = a1 + bb;
    P[(size_t)(row0 + 2) * OUT_F + f] = a2 + bb;
    P[(size_t)(row0 + 3) * OUT_F + f] = a3 + bb;
}

// ---------------- reductions over a 128-thread block (2 waves) ----------------
__device__ __forceinline__ float red_sum128(float v, float* red, int tid)
{
    #pragma unroll
    for (int off = 32; off; off >>= 1) v += __shfl_down(v, off);
    __syncthreads();                       // previous consumers of red done
    if ((tid & 63) == 0) red[tid >> 6] = v;
    __syncthreads();
    return red[0] + red[1];
}

__device__ __forceinline__ float red_max128(float v, float* red, int tid)
{
    #pragma unroll
    for (int off = 32; off; off >>= 1) v = fmaxf(v, __shfl_down(v, off));
    __syncthreads();
    if ((tid & 63) == 0) red[tid >> 6] = v;
    __syncthreads();
    return fmaxf(red[0], red[1]);
}

// ---------------- K2: normalize + KDE pdf + softmax + segment accumulate ----------------
__global__ __launch_bounds__(128) void pdf_kernel(
    const float* __restrict__ P, const int* __restrict__ Y1, const int* __restrict__ Y2,
    const float* __restrict__ bins, float* __restrict__ dist, float* __restrict__ counts)
{
    __shared__ float xn[OUT_F];
    __shared__ float red[2];
    const int j = threadIdx.x;
    const int row = blockIdx.x;            // 0..8191
    const int batch = row >> 12;           // row / 4096
    const int lrow = row & 4095;

    float p = P[(size_t)row * OUT_F + j];
    float nrm2 = red_sum128(p * p, red, j);
    float inv = 1.0f / sqrtf(nrm2);
    xn[j] = p * inv;
    __syncthreads();

    const float bj = bins[j];
    float acc = 0.f;
    #pragma unroll 8
    for (int d = 0; d < OUT_F; ++d) {
        float t = (xn[d] - bj) * (1.0f / SIGMA);
        acc += __expf(-0.5f * t * t);
    }
    float pdf = acc * (1.0f / OUT_F);

    float s = red_sum128(pdf, red, j);
    pdf = pdf / (s + EPSV);

    float m = red_max128(pdf, red, j);
    float e = __expf(pdf - m);
    float es = red_sum128(e, red, j);
    float sm = e / es;

    int cls = (batch == 0 ? Y1 : Y2)[lrow];
    atomicAdd(&dist[(size_t)(batch * NCLS + cls) * NBINS + j], sm);
    if (j == 0) atomicAdd(&counts[batch * NCLS + cls], 1.0f);
}

// ---------------- K3: class means, KL matrix, loss ----------------
__global__ __launch_bounds__(256) void final_kernel(
    const float* __restrict__ dist, const float* __restrict__ counts,
    float* __restrict__ out)
{
    __shared__ float PA[32][NBINS], LA[32][NBINS];
    __shared__ float PB[32][NBINS], LB[32][NBINS];
    __shared__ float J[32][32];
    __shared__ float pls[32];
    const int tid = threadIdx.x;

    for (int idx = tid; idx < NCLS * NBINS; idx += 256) {
        int c = idx >> 7, j = idx & 127;
        float a = dist[idx] / counts[c];                 // batch A class mean
        float b = dist[NCLS * NBINS + idx] / counts[NCLS + c]; // batch B
        float mm = 0.5f * (a + b);
        PA[c][j] = a;       LA[c][j] = logf(a);
        PA[c + 16][j] = mm; LA[c + 16][j] = logf(mm);
        PB[c][j] = b;       LB[c][j] = logf(b);
        PB[c + 16][j] = mm; LB[c + 16][j] = logf(mm);
    }
    __syncthreads();

    for (int pair = tid; pair < 32 * 32; pair += 256) {
        int i = pair >> 5, k = pair & 31;
        if (i == k) { J[i][k] = 0.f; continue; }
        float sA = 0.f, sB = 0.f;
        for (int j = 0; j < NBINS; ++j) {
            sA += PA[i][j] * (LA[i][j] - LA[k][j]);
            sB += PB[i][j] * (LB[i][j] - LB[k][j]);
        }
        J[i][k] = 0.5f * (sA + sB);
    }
    __syncthreads();

    if (tid < 32) {
        float den = 0.f;
        for (int k = 0; k < 32; ++k) den += __expf(J[tid][k] * (1.0f / TAUV));
        float pos = J[tid][(tid + 16) & 31];
        pls[tid] = -(pos * (1.0f / TAUV)) + logf(den);
    }
    __syncthreads();
    if (tid == 0) {
        float s = 0.f;
        for (int i = 0; i < 32; ++i) s += pls[i];
        out[0] = s * (1.0f / 32.0f);
    }
}

extern "C" void kernel_launch(void* const* d_in, const int* in_sizes, int n_in,
                              void* d_out, int out_size, void* d_ws, size_t ws_size,
                              hipStream_t stream)
{
    const float* x1   = (const float*)d_in[0];
    const int*   y1   = (const int*)d_in[1];
    const float* x2   = (const float*)d_in[2];
    const int*   y2   = (const int*)d_in[3];
    const float* W1   = (const float*)d_in[4];
    const float* b1   = (const float*)d_in[5];
    const float* W2   = (const float*)d_in[6];
    const float* b2   = (const float*)d_in[7];
    const float* bins = (const float*)d_in[8];
    float* out = (float*)d_out;

    char* ws = (char*)d_ws;
    float* P      = (float*)ws;                                   // 8192*128 floats = 4 MB
    float* dist   = (float*)(ws + (size_t)8192 * 128 * sizeof(float)); // 2*16*128
    float* counts = dist + 2 * NCLS * NBINS;                      // 2*16

    hipMemsetAsync(dist, 0, (2 * NCLS * NBINS + 2 * NCLS) * sizeof(float), stream);

    proj_kernel<<<2048, 128, 0, stream>>>(x1, x2, W1, b1, W2, b2, P);
    pdf_kernel<<<8192, 128, 0, stream>>>(P, y1, y2, bins, dist, counts);
    final_kernel<<<1, 256, 0, stream>>>(dist, counts, out);
}